// Round 1
// baseline (843.397 us; speedup 1.0000x reference)
//
#include <hip/hip_runtime.h>
#include <math.h>

static constexpr int cN1 = 67584, cN2 = 6144, cN3 = 1024;
static constexpr int F_IN = 100, HID = 256, OUT = 47;

// ---------------- aggregation: mean of FAN gathered rows ----------------
// one wave per dst node; lanes cover the row as float2 (coalesced 400B/1KB row loads)
template<int F, int FAN>
__global__ void agg_kernel(const float* __restrict__ X, const int* __restrict__ src,
                           float* __restrict__ agg, int M)
{
    int wave = (int)((blockIdx.x * blockDim.x + threadIdx.x) >> 6);
    int lane = threadIdx.x & 63;
    if (wave >= M) return;
    const int* s = src + (size_t)wave * FAN;
    constexpr int F2 = F / 2;                      // float2 per row (50 or 128)
    float2 acc0 = {0.f, 0.f}, acc1 = {0.f, 0.f};
    #pragma unroll
    for (int k = 0; k < FAN; ++k) {
        const float2* row = (const float2*)(X + (size_t)s[k] * F);
        if (lane < F2)                { float2 v = row[lane];      acc0.x += v.x; acc0.y += v.y; }
        if (F2 > 64 && lane + 64 < F2){ float2 v = row[lane + 64]; acc1.x += v.x; acc1.y += v.y; }
    }
    const float inv = 1.0f / (float)FAN;
    float2* out = (float2*)(agg + (size_t)wave * F);
    if (lane < F2)                { float2 o = {acc0.x * inv, acc0.y * inv}; out[lane] = o; }
    if (F2 > 64 && lane + 64 < F2){ float2 o = {acc1.x * inv, acc1.y * inv}; out[lane + 64] = o; }
}

// ---------------- GEMM: C = maybe_relu([Aagg|Adst] @ [Wl;Wr] + b) ----------------
// BM=BN=64, BK=16, 256 threads, 4x4 microtile per thread. M must be divisible by 64.
// K1 must be divisible by 4. Handles K=2*K1 not divisible by BK via zero-fill.
template<int BM, int BN, int BK>
__launch_bounds__(256)
__global__ void sage_gemm(const float* __restrict__ Aagg, const float* __restrict__ Adst,
                          const float* __restrict__ Wl, const float* __restrict__ Wr,
                          const float* __restrict__ bias, float* __restrict__ C,
                          int M, int N, int K1, int relu)
{
    __shared__ float As[BK][BM + 4];   // A tile, transposed [k][i], padded
    __shared__ float Bs[BK][BN];
    const int tid = threadIdx.x;
    const int tx = tid & 15, ty = tid >> 4;
    const int m0 = blockIdx.y * BM;
    const int n0 = blockIdx.x * BN;
    const int K = 2 * K1;

    float acc[4][4] = {};
    const int a_i = tid >> 2;          // 0..63
    const int a_k = (tid & 3) * 4;     // 0,4,8,12

    for (int k0 = 0; k0 < K; k0 += BK) {
        // A tile: float4 per thread, dual-pointer select (agg half vs dst half)
        {
            int row = m0 + a_i;
            int k = k0 + a_k;
            float4 v = {0.f, 0.f, 0.f, 0.f};
            if (k < K) {
                const float* p = (k < K1) ? (Aagg + (size_t)row * K1 + k)
                                          : (Adst + (size_t)row * K1 + (k - K1));
                v = *(const float4*)p;
            }
            As[a_k + 0][a_i] = v.x;
            As[a_k + 1][a_i] = v.y;
            As[a_k + 2][a_i] = v.z;
            As[a_k + 3][a_i] = v.w;
        }
        // B tile: 4 coalesced scalars per thread (handles N=47 bounds)
        #pragma unroll
        for (int r = 0; r < (BK * BN) / 256; ++r) {
            int f = tid + 256 * r;
            int kk = f / BN, j = f - kk * BN;
            int k = k0 + kk, jg = n0 + j;
            float v = 0.f;
            if (k < K && jg < N)
                v = (k < K1) ? Wl[(size_t)k * N + jg] : Wr[(size_t)(k - K1) * N + jg];
            Bs[kk][j] = v;
        }
        __syncthreads();
        #pragma unroll
        for (int kk = 0; kk < BK; ++kk) {
            float4 av = *(const float4*)&As[kk][ty * 4];
            float4 bv = *(const float4*)&Bs[kk][tx * 4];
            float a[4] = {av.x, av.y, av.z, av.w};
            float b[4] = {bv.x, bv.y, bv.z, bv.w};
            #pragma unroll
            for (int mi = 0; mi < 4; ++mi)
                #pragma unroll
                for (int ni = 0; ni < 4; ++ni)
                    acc[mi][ni] += a[mi] * b[ni];
        }
        __syncthreads();
    }

    const int rowb = m0 + ty * 4;
    const int colb = n0 + tx * 4;
    #pragma unroll
    for (int mi = 0; mi < 4; ++mi) {
        float* cp = C + (size_t)(rowb + mi) * N;
        if ((N & 3) == 0) {           // N divisible by 4: rows 16B-aligned, full tile in-bounds
            float4 o;
            o.x = acc[mi][0] + bias[colb + 0];
            o.y = acc[mi][1] + bias[colb + 1];
            o.z = acc[mi][2] + bias[colb + 2];
            o.w = acc[mi][3] + bias[colb + 3];
            if (relu) { o.x = fmaxf(o.x, 0.f); o.y = fmaxf(o.y, 0.f);
                        o.z = fmaxf(o.z, 0.f); o.w = fmaxf(o.w, 0.f); }
            *(float4*)(cp + colb) = o;
        } else {
            #pragma unroll
            for (int ni = 0; ni < 4; ++ni) {
                int col = colb + ni;
                if (col < N) {
                    float o = acc[mi][ni] + bias[col];
                    if (relu) o = fmaxf(o, 0.f);
                    cp[col] = o;
                }
            }
        }
    }
}

// ---------------- log_softmax over rows of N<=64 cols, one wave per row ----------------
__global__ void logsoftmax_kernel(float* __restrict__ out, int M, int N)
{
    int wave = (int)((blockIdx.x * blockDim.x + threadIdx.x) >> 6);
    int lane = threadIdx.x & 63;
    if (wave >= M) return;
    float* row = out + (size_t)wave * N;
    float v = (lane < N) ? row[lane] : -INFINITY;
    float m = v;
    #pragma unroll
    for (int off = 32; off; off >>= 1) m = fmaxf(m, __shfl_xor(m, off));
    float e = (lane < N) ? expf(v - m) : 0.f;
    float s = e;
    #pragma unroll
    for (int off = 32; off; off >>= 1) s += __shfl_xor(s, off);
    float ls = logf(s);
    if (lane < N) row[lane] = v - m - ls;
}

extern "C" void kernel_launch(void* const* d_in, const int* in_sizes, int n_in,
                              void* d_out, int out_size, void* d_ws, size_t ws_size,
                              hipStream_t stream)
{
    const float* x    = (const float*)d_in[0];
    const float* W_l1 = (const float*)d_in[1];
    const float* W_r1 = (const float*)d_in[2];
    const float* b1   = (const float*)d_in[3];
    const float* W_l2 = (const float*)d_in[4];
    const float* W_r2 = (const float*)d_in[5];
    const float* b2   = (const float*)d_in[6];
    const float* W_l3 = (const float*)d_in[7];
    const float* W_r3 = (const float*)d_in[8];
    const float* b3   = (const float*)d_in[9];
    const int* src1 = (const int*)d_in[10];
    const int* src2 = (const int*)d_in[12];
    const int* src3 = (const int*)d_in[14];

    float* ws = (float*)d_ws;
    // region plan (floats): [0, 6,758,400) agg1 -> later agg2/h2/agg3; [6,758,400, 24,059,904) h1
    float* agg1 = ws;                               // cN1*100
    float* h1   = ws + (size_t)cN1 * F_IN;          // cN1*256
    float* agg2 = ws;                               // cN2*256 (agg1 dead)
    float* h2   = ws + (size_t)cN2 * HID;           // cN2*256
    float* agg3 = h2 + (size_t)cN2 * HID;           // cN3*256
    float* out  = (float*)d_out;

    // layer 1
    agg_kernel<F_IN, 15><<<cN1 / 4, 256, 0, stream>>>(x, src1, agg1, cN1);
    {
        dim3 g(HID / 64, cN1 / 64);
        sage_gemm<64, 64, 16><<<g, 256, 0, stream>>>(agg1, x, W_l1, W_r1, b1, h1, cN1, HID, F_IN, 1);
    }
    // layer 2
    agg_kernel<HID, 10><<<cN2 / 4, 256, 0, stream>>>(h1, src2, agg2, cN2);
    {
        dim3 g(HID / 64, cN2 / 64);
        sage_gemm<64, 64, 16><<<g, 256, 0, stream>>>(agg2, h1, W_l2, W_r2, b2, h2, cN2, HID, HID, 1);
    }
    // layer 3
    agg_kernel<HID, 5><<<cN3 / 4, 256, 0, stream>>>(h2, src3, agg3, cN3);
    {
        dim3 g(1, cN3 / 64);
        sage_gemm<64, 64, 16><<<g, 256, 0, stream>>>(agg3, h2, W_l3, W_r3, b3, out, cN3, OUT, HID, 0);
    }
    logsoftmax_kernel<<<cN3 / 4, 256, 0, stream>>>(out, cN3, OUT);
}

// Round 2
// 687.019 us; speedup vs baseline: 1.2276x; 1.2276x over previous
//
#include <hip/hip_runtime.h>
#include <math.h>

static constexpr int cN1 = 67584, cN2 = 6144, cN3 = 1024;
static constexpr int F_IN = 100, HID = 256, OUT = 47;
static constexpr int K1P = 224;   // layer-1 K padded to multiple of 32 (100+100+24 zeros)

typedef __attribute__((ext_vector_type(8))) short short8;   // 8 bf16 (4 VGPRs) MFMA A/B frag
typedef __attribute__((ext_vector_type(4))) float float4v;  // MFMA C/D frag

__device__ __forceinline__ ushort f2b(float f) {            // f32 -> bf16 RNE
    unsigned u = __builtin_bit_cast(unsigned, f);
    u += 0x7fff + ((u >> 16) & 1);
    return (ushort)(u >> 16);
}
__device__ __forceinline__ float b2f(ushort h) {
    unsigned u = ((unsigned)h) << 16;
    return __builtin_bit_cast(float, u);
}

// ---------------- build A1 = [mean15(gather x) | x_dst | 0pad] as bf16 [cN1 x 224] ----------------
__global__ void build_A1(const float* __restrict__ x, const int* __restrict__ src,
                         ushort* __restrict__ A1)
{
    int wave = (int)((blockIdx.x * blockDim.x + threadIdx.x) >> 6);
    int lane = threadIdx.x & 63;
    if (wave >= cN1) return;
    const int* s = src + (size_t)wave * 15;
    float ax = 0.f, ay = 0.f;
    #pragma unroll
    for (int k = 0; k < 15; ++k) {
        const float2* row = (const float2*)(x + (size_t)s[k] * F_IN);
        if (lane < 50) { float2 v = row[lane]; ax += v.x; ay += v.y; }
    }
    ushort* out = A1 + (size_t)wave * K1P;
    if (lane < 50) {
        float2 o = ((const float2*)(x + (size_t)wave * F_IN))[lane];
        ushort2 m; m.x = f2b(ax * (1.0f / 15.0f)); m.y = f2b(ay * (1.0f / 15.0f));
        ((ushort2*)out)[lane] = m;
        ushort2 d; d.x = f2b(o.x); d.y = f2b(o.y);
        *(ushort2*)(out + 100 + 2 * lane) = d;
    } else if (lane < 62) {               // zero cols 200..223
        ushort2 z; z.x = 0; z.y = 0;
        *(ushort2*)(out + 200 + 2 * (lane - 50)) = z;
    }
}

// ---------------- build A = [meanFAN(gather H) | H_dst] as bf16 [M x 512], H is bf16 [ * x 256] ----
template<int FAN>
__global__ void build_A(const ushort* __restrict__ H, const int* __restrict__ src,
                        ushort* __restrict__ A, int M)
{
    int wave = (int)((blockIdx.x * blockDim.x + threadIdx.x) >> 6);
    int lane = threadIdx.x & 63;
    if (wave >= M) return;
    const int* s = src + (size_t)wave * FAN;
    float a0 = 0.f, a1 = 0.f, a2 = 0.f, a3 = 0.f;
    #pragma unroll
    for (int k = 0; k < FAN; ++k) {
        ushort4 v = ((const ushort4*)(H + (size_t)s[k] * HID))[lane];
        a0 += b2f(v.x); a1 += b2f(v.y); a2 += b2f(v.z); a3 += b2f(v.w);
    }
    const float inv = 1.0f / (float)FAN;
    ushort4 own = ((const ushort4*)(H + (size_t)wave * HID))[lane];
    ushort* out = A + (size_t)wave * (2 * HID);
    ushort4 m; m.x = f2b(a0 * inv); m.y = f2b(a1 * inv); m.z = f2b(a2 * inv); m.w = f2b(a3 * inv);
    ((ushort4*)out)[lane] = m;
    ((ushort4*)(out + HID))[lane] = own;
}

// ---------------- weight convert+transpose: Bt[n][k] bf16, [Npad x Kpad] ----------------
__global__ void conv_W(const float* __restrict__ Wl, const float* __restrict__ Wr,
                       ushort* __restrict__ Bt, int K1, int N, int Npad, int Kpad)
{
    int idx = blockIdx.x * blockDim.x + threadIdx.x;
    if (idx >= Npad * Kpad) return;
    int n = idx / Kpad, k = idx - n * Kpad;
    float v = 0.f;
    if (n < N) {
        if (k < K1)           v = Wl[(size_t)k * N + n];
        else if (k < 2 * K1)  v = Wr[(size_t)(k - K1) * N + n];
    }
    Bt[idx] = f2b(v);
}

// ---------------- MFMA GEMM: C = maybe_relu(A @ B + bias) ----------------
// A bf16 [M x K] row-major; Bt bf16 [Npad x K] (B transposed); 128x128x32 tile, 256 thr = 4 waves,
// each wave 64x64 via 4x4 grid of 16x16x32 MFMAs. M%128==0, K%32==0, Npad>=grid.x*128.
template<bool OUT_BF16, bool RELU>
__launch_bounds__(256)
__global__ void mfma_gemm(const ushort* __restrict__ A, const ushort* __restrict__ Bt,
                          const float* __restrict__ bias, void* __restrict__ Cout,
                          int M, int N, int K)
{
    constexpr int BM = 128, BK = 32, SA = BK + 8;      // +8 bf16 pad vs bank conflicts
    __shared__ ushort As[BM * SA];
    __shared__ ushort Bs[BM * SA];
    const int tid  = threadIdx.x;
    const int m0   = blockIdx.y * BM;
    const int n0   = blockIdx.x * BM;
    const int lane = tid & 63;
    const int w    = tid >> 6;
    const int wr   = (w >> 1) * 64;      // wave row origin in tile
    const int wc   = (w & 1) * 64;       // wave col origin in tile
    const int m_in = lane & 15;
    const int k8   = (lane >> 4) * 8;
    const int srow = tid >> 1;           // staging: row 0..127
    const int skc  = (tid & 1) * 16;     // staging: k-chunk 0 or 16

    float4v acc[4][4] = {};

    const ushort* gA = A  + (size_t)(m0 + srow) * K + skc;
    const ushort* gB = Bt + (size_t)(n0 + srow) * K + skc;

    for (int k0 = 0; k0 < K; k0 += BK) {
        float4 a0 = ((const float4*)(gA + k0))[0];
        float4 a1 = ((const float4*)(gA + k0))[1];
        float4 b0 = ((const float4*)(gB + k0))[0];
        float4 b1 = ((const float4*)(gB + k0))[1];
        __syncthreads();
        *(float4*)&As[srow * SA + skc]     = a0;
        *(float4*)&As[srow * SA + skc + 8] = a1;
        *(float4*)&Bs[srow * SA + skc]     = b0;
        *(float4*)&Bs[srow * SA + skc + 8] = b1;
        __syncthreads();
        short8 af[4], bf[4];
        #pragma unroll
        for (int i = 0; i < 4; ++i) {
            af[i] = *(const short8*)&As[(wr + i * 16 + m_in) * SA + k8];
            bf[i] = *(const short8*)&Bs[(wc + i * 16 + m_in) * SA + k8];
        }
        #pragma unroll
        for (int mi = 0; mi < 4; ++mi)
            #pragma unroll
            for (int ni = 0; ni < 4; ++ni)
                acc[mi][ni] = __builtin_amdgcn_mfma_f32_16x16x32_bf16(af[mi], bf[ni], acc[mi][ni], 0, 0, 0);
    }

    // epilogue: C/D layout col=lane&15, row=(lane>>4)*4+r  [m89/m91-verified]
    #pragma unroll
    for (int ni = 0; ni < 4; ++ni) {
        int col = n0 + wc + ni * 16 + m_in;
        if (col >= N) continue;
        float bv = bias[col];
        #pragma unroll
        for (int mi = 0; mi < 4; ++mi) {
            #pragma unroll
            for (int r = 0; r < 4; ++r) {
                int row = m0 + wr + mi * 16 + (lane >> 4) * 4 + r;
                float v = acc[mi][ni][r] + bv;
                if (RELU) v = fmaxf(v, 0.f);
                if (OUT_BF16) ((ushort*)Cout)[(size_t)row * N + col] = f2b(v);
                else          ((float*)Cout)[(size_t)row * N + col] = v;
            }
        }
    }
}

// ---------------- log_softmax over rows of N<=64 cols, one wave per row ----------------
__global__ void logsoftmax_kernel(float* __restrict__ out, int M, int N)
{
    int wave = (int)((blockIdx.x * blockDim.x + threadIdx.x) >> 6);
    int lane = threadIdx.x & 63;
    if (wave >= M) return;
    float* row = out + (size_t)wave * N;
    float v = (lane < N) ? row[lane] : -INFINITY;
    float m = v;
    #pragma unroll
    for (int off = 32; off; off >>= 1) m = fmaxf(m, __shfl_xor(m, off));
    float e = (lane < N) ? expf(v - m) : 0.f;
    float s = e;
    #pragma unroll
    for (int off = 32; off; off >>= 1) s += __shfl_xor(s, off);
    float ls = logf(s);
    if (lane < N) row[lane] = v - m - ls;
}

extern "C" void kernel_launch(void* const* d_in, const int* in_sizes, int n_in,
                              void* d_out, int out_size, void* d_ws, size_t ws_size,
                              hipStream_t stream)
{
    const float* x    = (const float*)d_in[0];
    const float* W_l1 = (const float*)d_in[1];
    const float* W_r1 = (const float*)d_in[2];
    const float* b1   = (const float*)d_in[3];
    const float* W_l2 = (const float*)d_in[4];
    const float* W_r2 = (const float*)d_in[5];
    const float* b2   = (const float*)d_in[6];
    const float* W_l3 = (const float*)d_in[7];
    const float* W_r3 = (const float*)d_in[8];
    const float* b3   = (const float*)d_in[9];
    const int* src1 = (const int*)d_in[10];
    const int* src2 = (const int*)d_in[12];
    const int* src3 = (const int*)d_in[14];
    float* out = (float*)d_out;

    // workspace layout (all bf16/ushort, every offset 16B-aligned)
    ushort* ws  = (ushort*)d_ws;
    ushort* A1  = ws;                                  // [cN1 x 224]
    ushort* h1  = A1  + (size_t)cN1 * K1P;             // [cN1 x 256]
    ushort* A2  = h1  + (size_t)cN1 * HID;             // [cN2 x 512]
    ushort* h2  = A2  + (size_t)cN2 * 2 * HID;         // [cN2 x 256]
    ushort* A3  = h2  + (size_t)cN2 * HID;             // [cN3 x 512]
    ushort* Bt1 = A3  + (size_t)cN3 * 2 * HID;         // [256 x 224]
    ushort* Bt2 = Bt1 + (size_t)256 * K1P;             // [256 x 512]
    ushort* Bt3 = Bt2 + (size_t)256 * 2 * HID;         // [128 x 512]

    // weight conversion (tiny)
    conv_W<<<(256 * K1P + 255) / 256, 256, 0, stream>>>(W_l1, W_r1, Bt1, F_IN, HID, 256, K1P);
    conv_W<<<(256 * 512 + 255) / 256, 256, 0, stream>>>(W_l2, W_r2, Bt2, HID, HID, 256, 512);
    conv_W<<<(128 * 512 + 255) / 256, 256, 0, stream>>>(W_l3, W_r3, Bt3, HID, OUT, 128, 512);

    // layer 1
    build_A1<<<cN1 / 4, 256, 0, stream>>>(x, src1, A1);
    mfma_gemm<true, true><<<dim3(2, cN1 / 128), 256, 0, stream>>>(A1, Bt1, b1, h1, cN1, HID, K1P);
    // layer 2
    build_A<10><<<cN2 / 4, 256, 0, stream>>>(h1, src2, A2, cN2);
    mfma_gemm<true, true><<<dim3(2, cN2 / 128), 256, 0, stream>>>(A2, Bt2, b2, h2, cN2, HID, 512);
    // layer 3
    build_A<5><<<cN3 / 4, 256, 0, stream>>>(h2, src3, A3, cN3);
    mfma_gemm<false, false><<<dim3(1, cN3 / 128), 256, 0, stream>>>(A3, Bt3, b3, out, cN3, OUT, 512);
    logsoftmax_kernel<<<cN3 / 4, 256, 0, stream>>>(out, cN3, OUT);
}

// Round 3
// 654.555 us; speedup vs baseline: 1.2885x; 1.0496x over previous
//
#include <hip/hip_runtime.h>
#include <math.h>

static constexpr int cN1 = 67584, cN2 = 6144, cN3 = 1024;
static constexpr int F_IN = 100, HID = 256, OUT = 47;
static constexpr int K1P = 224;   // layer-1 K padded to multiple of 32 (100+100+24 zeros)

typedef __attribute__((ext_vector_type(8))) short short8;   // 8 bf16 (4 VGPRs) MFMA A/B frag
typedef __attribute__((ext_vector_type(4))) float float4v;  // MFMA C/D frag

__device__ __forceinline__ ushort f2b(float f) {            // f32 -> bf16 RNE
    unsigned u = __builtin_bit_cast(unsigned, f);
    u += 0x7fff + ((u >> 16) & 1);
    return (ushort)(u >> 16);
}
__device__ __forceinline__ unsigned pack2(float a, float b) {
    return (unsigned)f2b(a) | ((unsigned)f2b(b) << 16);
}

// ---------------- build A1 = [mean15(gather x) | x_dst | 0pad] as bf16 [cN1 x 224] ----------------
// one wave per dst node; half-wave 0 = even edges, half-wave 1 = odd edges; float4 loads (16B/lane)
__global__ void build_A1(const float* __restrict__ x, const int* __restrict__ src,
                         ushort* __restrict__ A1)
{
    int wave = (int)((blockIdx.x * blockDim.x + threadIdx.x) >> 6);
    int lane = threadIdx.x & 63;
    if (wave >= cN1) return;
    const int* s = src + (size_t)wave * 15;
    const int half = lane >> 5, hl = lane & 31;
    const bool act = hl < 25;                       // 25 float4 per 100-float row
    float4 own = {0.f, 0.f, 0.f, 0.f};
    if (half == 1 && act)
        own = *(const float4*)(x + (size_t)wave * F_IN + 4 * hl);
    float4 acc = {0.f, 0.f, 0.f, 0.f};
    #pragma unroll
    for (int j = 0; j < 8; ++j) {
        int e = 2 * j + half;                       // half0: 0,2,..,14 ; half1: 1,3,..,13
        if (e < 15 && act) {
            float4 v = *(const float4*)(x + (size_t)s[e] * F_IN + 4 * hl);
            acc.x += v.x; acc.y += v.y; acc.z += v.z; acc.w += v.w;
        }
    }
    acc.x += __shfl(acc.x, lane ^ 32);
    acc.y += __shfl(acc.y, lane ^ 32);
    acc.z += __shfl(acc.z, lane ^ 32);
    acc.w += __shfl(acc.w, lane ^ 32);
    ushort* outp = A1 + (size_t)wave * K1P;
    constexpr float inv = 1.0f / 15.0f;
    if (half == 0) {
        if (act) {
            ushort4 m; m.x = f2b(acc.x * inv); m.y = f2b(acc.y * inv);
                       m.z = f2b(acc.z * inv); m.w = f2b(acc.w * inv);
            *(ushort4*)(outp + 4 * hl) = m;
        }
    } else {
        if (act) {
            ushort4 d; d.x = f2b(own.x); d.y = f2b(own.y); d.z = f2b(own.z); d.w = f2b(own.w);
            *(ushort4*)(outp + 100 + 4 * hl) = d;
        } else if (hl < 31) {                       // zero cols 200..223 (6 lanes x 4 ushorts)
            ushort4 z; z.x = 0; z.y = 0; z.z = 0; z.w = 0;
            *(ushort4*)(outp + 200 + 4 * (hl - 25)) = z;
        }
    }
}

// ---------------- build A = [meanFAN(gather H) | H_dst] bf16 [M x 512]; H bf16 [* x 256] ----------
// one wave per node; half-wave 0 = even edges, half-wave 1 = odd edges; float4 (16B) loads, all lanes
template<int FAN>
__global__ void build_A(const ushort* __restrict__ H, const int* __restrict__ src,
                        ushort* __restrict__ A, int M)
{
    int wave = (int)((blockIdx.x * blockDim.x + threadIdx.x) >> 6);
    int lane = threadIdx.x & 63;
    if (wave >= M) return;
    const int* s = src + (size_t)wave * FAN;
    const int half = lane >> 5, hl = lane & 31;     // 32 float4 per 256-bf16 row
    const float* Hf = (const float*)H;
    float4 own;
    if (half == 1)
        own = *(const float4*)(Hf + (size_t)wave * 128 + 4 * hl);
    float a[8] = {0.f, 0.f, 0.f, 0.f, 0.f, 0.f, 0.f, 0.f};
    constexpr int NJ = (FAN + 1) / 2;
    #pragma unroll
    for (int j = 0; j < NJ; ++j) {
        int e = 2 * j + half;
        if (e < FAN) {
            float4 v = *(const float4*)(Hf + (size_t)s[e] * 128 + 4 * hl);
            unsigned u;
            u = __builtin_bit_cast(unsigned, v.x);
            a[0] += __builtin_bit_cast(float, u << 16); a[1] += __builtin_bit_cast(float, u & 0xffff0000u);
            u = __builtin_bit_cast(unsigned, v.y);
            a[2] += __builtin_bit_cast(float, u << 16); a[3] += __builtin_bit_cast(float, u & 0xffff0000u);
            u = __builtin_bit_cast(unsigned, v.z);
            a[4] += __builtin_bit_cast(float, u << 16); a[5] += __builtin_bit_cast(float, u & 0xffff0000u);
            u = __builtin_bit_cast(unsigned, v.w);
            a[6] += __builtin_bit_cast(float, u << 16); a[7] += __builtin_bit_cast(float, u & 0xffff0000u);
        }
    }
    #pragma unroll
    for (int i = 0; i < 8; ++i) a[i] += __shfl(a[i], lane ^ 32);
    ushort* outp = A + (size_t)wave * (2 * HID);
    constexpr float inv = 1.0f / (float)FAN;
    if (half == 0) {
        uint4 w;
        w.x = pack2(a[0] * inv, a[1] * inv);
        w.y = pack2(a[2] * inv, a[3] * inv);
        w.z = pack2(a[4] * inv, a[5] * inv);
        w.w = pack2(a[6] * inv, a[7] * inv);
        *(uint4*)(outp + 8 * hl) = w;               // mean: bf16 cols 8hl..8hl+7
    } else {
        *(float4*)(outp + HID + 8 * hl) = own;      // raw bf16 copy of dst row
    }
}

// ---------------- fused weight convert+transpose for all 3 layers ----------------
static constexpr int S1 = 256 * K1P, S2 = 256 * 512, S3 = 128 * 512;
__global__ void conv_W_all(const float* __restrict__ Wl1, const float* __restrict__ Wr1,
                           const float* __restrict__ Wl2, const float* __restrict__ Wr2,
                           const float* __restrict__ Wl3, const float* __restrict__ Wr3,
                           ushort* __restrict__ Bt1, ushort* __restrict__ Bt2,
                           ushort* __restrict__ Bt3)
{
    int idx = blockIdx.x * 256 + threadIdx.x;
    if (idx < S1) {
        int n = idx / K1P, k = idx - n * K1P;
        float v = 0.f;
        if (k < 100)      v = Wl1[(size_t)k * 256 + n];
        else if (k < 200) v = Wr1[(size_t)(k - 100) * 256 + n];
        Bt1[idx] = f2b(v);
    } else if (idx < S1 + S2) {
        int i = idx - S1;
        int n = i >> 9, k = i & 511;
        float v = (k < 256) ? Wl2[(size_t)k * 256 + n] : Wr2[(size_t)(k - 256) * 256 + n];
        Bt2[i] = f2b(v);
    } else if (idx < S1 + S2 + S3) {
        int i = idx - S1 - S2;
        int n = i >> 9, k = i & 511;
        float v = 0.f;
        if (n < OUT) v = (k < 256) ? Wl3[(size_t)k * OUT + n] : Wr3[(size_t)(k - 256) * OUT + n];
        Bt3[i] = f2b(v);
    }
}

// ---------------- MFMA GEMM: C = maybe_relu(A @ B + bias), optional fused log_softmax ------------
// A bf16 [M x K] row-major; Bt bf16 [Npad x K]; 128x128x32 tile, 256 thr = 4 waves,
// each wave 64x64 via 4x4 grid of 16x16x32 MFMAs. M%128==0, K%32==0, Npad>=grid.x*128.
// LS requires N<=64 and grid.x==1 (full row per wave in wc==0 waves).
template<bool OUT_BF16, bool RELU, bool LS>
__launch_bounds__(256)
__global__ void mfma_gemm(const ushort* __restrict__ A, const ushort* __restrict__ Bt,
                          const float* __restrict__ bias, void* __restrict__ Cout,
                          int M, int N, int K)
{
    constexpr int BM = 128, BK = 32, SA = BK + 8;      // +8 bf16 pad vs bank conflicts
    __shared__ ushort As[BM * SA];
    __shared__ ushort Bs[BM * SA];
    const int tid  = threadIdx.x;
    const int m0   = blockIdx.y * BM;
    const int n0   = blockIdx.x * BM;
    const int lane = tid & 63;
    const int w    = tid >> 6;
    const int wr   = (w >> 1) * 64;      // wave row origin in tile
    const int wc   = (w & 1) * 64;       // wave col origin in tile
    const int m_in = lane & 15;
    const int k8   = (lane >> 4) * 8;
    const int srow = tid >> 1;           // staging: row 0..127
    const int skc  = (tid & 1) * 16;     // staging: k-chunk 0 or 16

    float4v acc[4][4] = {};

    const ushort* gA = A  + (size_t)(m0 + srow) * K + skc;
    const ushort* gB = Bt + (size_t)(n0 + srow) * K + skc;

    for (int k0 = 0; k0 < K; k0 += BK) {
        float4 a0 = ((const float4*)(gA + k0))[0];
        float4 a1 = ((const float4*)(gA + k0))[1];
        float4 b0 = ((const float4*)(gB + k0))[0];
        float4 b1 = ((const float4*)(gB + k0))[1];
        __syncthreads();
        *(float4*)&As[srow * SA + skc]     = a0;
        *(float4*)&As[srow * SA + skc + 8] = a1;
        *(float4*)&Bs[srow * SA + skc]     = b0;
        *(float4*)&Bs[srow * SA + skc + 8] = b1;
        __syncthreads();
        short8 af[4], bf[4];
        #pragma unroll
        for (int i = 0; i < 4; ++i) {
            af[i] = *(const short8*)&As[(wr + i * 16 + m_in) * SA + k8];
            bf[i] = *(const short8*)&Bs[(wc + i * 16 + m_in) * SA + k8];
        }
        #pragma unroll
        for (int mi = 0; mi < 4; ++mi)
            #pragma unroll
            for (int ni = 0; ni < 4; ++ni)
                acc[mi][ni] = __builtin_amdgcn_mfma_f32_16x16x32_bf16(af[mi], bf[ni], acc[mi][ni], 0, 0, 0);
    }

    // C/D layout: col=lane&15, row=(lane>>4)*4+r  [m89/m91-verified]
    if (LS) {
        // fused log_softmax over rows; only wc==0 waves hold cols 0..63 >= N
        if (wc != 0) return;
        #pragma unroll
        for (int mi = 0; mi < 4; ++mi) {
            #pragma unroll
            for (int r = 0; r < 4; ++r) {
                float v[4]; float mx = -3.0e38f;
                #pragma unroll
                for (int ni = 0; ni < 4; ++ni) {
                    int col = ni * 16 + m_in;
                    v[ni] = (col < N) ? acc[mi][ni][r] + bias[col] : -3.0e38f;
                    mx = fmaxf(mx, v[ni]);
                }
                #pragma unroll
                for (int off = 1; off < 16; off <<= 1) mx = fmaxf(mx, __shfl_xor(mx, off));
                float sum = 0.f;
                #pragma unroll
                for (int ni = 0; ni < 4; ++ni)
                    sum += (v[ni] > -1.0e38f) ? expf(v[ni] - mx) : 0.f;
                #pragma unroll
                for (int off = 1; off < 16; off <<= 1) sum += __shfl_xor(sum, off);
                float ls = logf(sum);
                int row = m0 + wr + mi * 16 + (lane >> 4) * 4 + r;
                #pragma unroll
                for (int ni = 0; ni < 4; ++ni) {
                    int col = ni * 16 + m_in;
                    if (col < N)
                        ((float*)Cout)[(size_t)row * N + col] = v[ni] - mx - ls;
                }
            }
        }
        return;
    }

    #pragma unroll
    for (int ni = 0; ni < 4; ++ni) {
        int col = n0 + wc + ni * 16 + m_in;
        if (col >= N) continue;
        float bv = bias[col];
        #pragma unroll
        for (int mi = 0; mi < 4; ++mi) {
            #pragma unroll
            for (int r = 0; r < 4; ++r) {
                int row = m0 + wr + mi * 16 + (lane >> 4) * 4 + r;
                float v = acc[mi][ni][r] + bv;
                if (RELU) v = fmaxf(v, 0.f);
                if (OUT_BF16) ((ushort*)Cout)[(size_t)row * N + col] = f2b(v);
                else          ((float*)Cout)[(size_t)row * N + col] = v;
            }
        }
    }
}

extern "C" void kernel_launch(void* const* d_in, const int* in_sizes, int n_in,
                              void* d_out, int out_size, void* d_ws, size_t ws_size,
                              hipStream_t stream)
{
    const float* x    = (const float*)d_in[0];
    const float* W_l1 = (const float*)d_in[1];
    const float* W_r1 = (const float*)d_in[2];
    const float* b1   = (const float*)d_in[3];
    const float* W_l2 = (const float*)d_in[4];
    const float* W_r2 = (const float*)d_in[5];
    const float* b2   = (const float*)d_in[6];
    const float* W_l3 = (const float*)d_in[7];
    const float* W_r3 = (const float*)d_in[8];
    const float* b3   = (const float*)d_in[9];
    const int* src1 = (const int*)d_in[10];
    const int* src2 = (const int*)d_in[12];
    const int* src3 = (const int*)d_in[14];
    float* out = (float*)d_out;

    // workspace layout (all bf16/ushort, every offset 16B-aligned)
    ushort* ws  = (ushort*)d_ws;
    ushort* A1  = ws;                                  // [cN1 x 224]
    ushort* h1  = A1  + (size_t)cN1 * K1P;             // [cN1 x 256]
    ushort* A2  = h1  + (size_t)cN1 * HID;             // [cN2 x 512]
    ushort* h2  = A2  + (size_t)cN2 * 2 * HID;         // [cN2 x 256]
    ushort* A3  = h2  + (size_t)cN2 * HID;             // [cN3 x 512]
    ushort* Bt1 = A3  + (size_t)cN3 * 2 * HID;         // [256 x 224]
    ushort* Bt2 = Bt1 + (size_t)256 * K1P;             // [256 x 512]
    ushort* Bt3 = Bt2 + (size_t)256 * 2 * HID;         // [128 x 512]

    conv_W_all<<<(S1 + S2 + S3 + 255) / 256, 256, 0, stream>>>(
        W_l1, W_r1, W_l2, W_r2, W_l3, W_r3, Bt1, Bt2, Bt3);

    // layer 1
    build_A1<<<cN1 / 4, 256, 0, stream>>>(x, src1, A1);
    mfma_gemm<true, true, false><<<dim3(2, cN1 / 128), 256, 0, stream>>>(A1, Bt1, b1, h1, cN1, HID, K1P);
    // layer 2
    build_A<10><<<cN2 / 4, 256, 0, stream>>>(h1, src2, A2, cN2);
    mfma_gemm<true, true, false><<<dim3(2, cN2 / 128), 256, 0, stream>>>(A2, Bt2, b2, h2, cN2, HID, 512);
    // layer 3 (+ fused log_softmax)
    build_A<5><<<cN3 / 4, 256, 0, stream>>>(h2, src3, A3, cN3);
    mfma_gemm<false, false, true><<<dim3(1, cN3 / 128), 256, 0, stream>>>(A3, Bt3, b3, out, cN3, OUT, 512);
}